// Round 16
// baseline (524.082 us; speedup 1.0000x reference)
//
#include <hip/hip_runtime.h>

typedef unsigned short u16;
typedef __attribute__((ext_vector_type(8))) short bf16x8;
typedef __attribute__((ext_vector_type(8))) unsigned short u16x8;
typedef __attribute__((ext_vector_type(4))) unsigned short u16x4;
typedef __attribute__((ext_vector_type(4))) float f32x4;

__device__ __forceinline__ u16 f2bf(float f) {
  union { float f; unsigned u; } v; v.f = f;
  unsigned r = v.u + 0x7fffu + ((v.u >> 16) & 1u);
  return (u16)(r >> 16);
}

__device__ __forceinline__ void gload16(const u16* g, u16* l) {
  __builtin_amdgcn_global_load_lds((const __attribute__((address_space(1))) void*)g,
                                   (__attribute__((address_space(3))) void*)l, 16, 0, 0);
}

// ---------------- fused prep: cast hs + 4 transpose-casts, one launch ----------------
__device__ __forceinline__ void transpose_body(const float* __restrict__ in,
                                               u16* __restrict__ out, int K, int N,
                                               int bid, float (*tile)[65]) {
  int nbx = N >> 6;
  int n0 = (bid % nbx) << 6;
  int k0 = (bid / nbx) << 6;
  int tx = threadIdx.x & 15;
  int ty = threadIdx.x >> 4;
#pragma unroll
  for (int r = 0; r < 64; r += 16) {
    float4 v = *(const float4*)(in + (size_t)(k0 + ty + r) * N + n0 + tx * 4);
    tile[ty + r][tx * 4 + 0] = v.x;
    tile[ty + r][tx * 4 + 1] = v.y;
    tile[ty + r][tx * 4 + 2] = v.z;
    tile[ty + r][tx * 4 + 3] = v.w;
  }
  __syncthreads();
#pragma unroll
  for (int r = 0; r < 64; r += 16) {
    u16x4 o;
#pragma unroll
    for (int j = 0; j < 4; j++) o[j] = f2bf(tile[tx * 4 + j][ty + r]);
    *(u16x4*)(out + (size_t)(n0 + ty + r) * K + k0 + tx * 4) = o;
  }
}

__global__ __launch_bounds__(256) void prep_kern(const float* __restrict__ hs,
                                                 const float* __restrict__ wq,
                                                 const float* __restrict__ wk,
                                                 const float* __restrict__ wv,
                                                 const float* __restrict__ wo,
                                                 u16* __restrict__ hs_b,
                                                 u16* __restrict__ wqT,
                                                 u16* __restrict__ wkT,
                                                 u16* __restrict__ wvT,
                                                 u16* __restrict__ woT) {
  __shared__ float tile[64][65];
  int b = blockIdx.x;
  if (b < 8192) {
    int i = (b * 256 + threadIdx.x) * 8;
    float4 a = *(const float4*)(hs + i);
    float4 c = *(const float4*)(hs + i + 4);
    u16x8 r;
    r[0] = f2bf(a.x); r[1] = f2bf(a.y); r[2] = f2bf(a.z); r[3] = f2bf(a.w);
    r[4] = f2bf(c.x); r[5] = f2bf(c.y); r[6] = f2bf(c.z); r[7] = f2bf(c.w);
    *(u16x8*)(hs_b + i) = r;
  } else if (b < 12288) {
    transpose_body(wq, wqT, 4096, 4096, b - 8192, tile);
  } else if (b < 13312) {
    transpose_body(wk, wkT, 4096, 1024, b - 12288, tile);
  } else if (b < 14336) {
    transpose_body(wv, wvT, 4096, 1024, b - 13312, tile);
  } else {
    transpose_body(wo, woT, 4096, 4096, b - 14336, tile);
  }
}

// ---- phase fences (measured-best round-7 structure) ----
#define PH_PRE()                                           \
  asm volatile("" ::: "memory");                           \
  __builtin_amdgcn_s_barrier();                            \
  asm volatile("" ::: "memory");                           \
  __builtin_amdgcn_s_setprio(1)

#define PH_POST()                                          \
  __builtin_amdgcn_s_setprio(0);                           \
  asm volatile("" ::: "memory");                           \
  __builtin_amdgcn_s_barrier();                            \
  asm volatile("" ::: "memory")

// ---------------- 256^2 8-phase GEMM ----------------
// MODE 0: bf16 C row-major. MODE 2: f32 C. MODE 3: fused QKV epilogue
// (gn<4096 -> Q bf16 [M][4096]; gn<5120 -> K [M][1024]; else V^T permuted).
template <int MODE>
__global__ __launch_bounds__(512, 2) void gemm256(const u16* __restrict__ A,
                                                  const u16* __restrict__ Bt,
                                                  void* __restrict__ Cout,
                                                  void* __restrict__ C2,
                                                  void* __restrict__ C3,
                                                  int M, int N, int K) {
  __shared__ u16 lds[65536];  // 128 KiB: A at 0, B at 32768 (u16 units)
  const int tid = threadIdx.x;
  const int lane = tid & 63, w = tid >> 6;
  const int wm = w >> 2, wn = w & 3;
  const int li = lane & 15, lg = lane >> 4;
  const int NT = K >> 6;

  const int nbx = N >> 8;
  const int nwg = gridDim.x;
  const int swz = (blockIdx.x & 7) * (nwg >> 3) + (blockIdx.x >> 3);  // XCD swizzle (nwg%8==0)
  const int m0 = (swz / nbx) << 8;
  const int n0 = (swz % nbx) << 8;

  const int srow = w * 16 + (lane >> 3);
  const int scol = ((lane & 7) ^ (lane >> 3)) << 3;
  const u16* sA0 = A + (size_t)(m0 + srow) * K + scol;
  const u16* sA1 = A + (size_t)(m0 + 128 + srow) * K + scol;
  const u16* sB0 = Bt + (size_t)(n0 + srow) * K + scol;
  const u16* sB1 = Bt + (size_t)(n0 + 128 + srow) * K + scol;
  const size_t jK = (size_t)8 * K;
  u16* dA0 = lds + w * 1024;
  u16* dA1 = lds + 8192 + w * 1024;
  u16* dB0 = lds + 32768 + w * 1024;
  u16* dB1 = lds + 32768 + 8192 + w * 1024;

#define STG(sp, dp, t_) do {                                          \
    int db_ = (t_) & 1;                                               \
    gload16((sp) + (size_t)(t_) * 64, (dp) + db_ * 16384);            \
    gload16((sp) + (size_t)(t_) * 64 + jK, (dp) + db_ * 16384 + 512); \
  } while (0)

  STG(sA0, dA0, 0); STG(sA1, dA1, 0); STG(sB0, dB0, 0); STG(sB1, dB1, 0);
  STG(sA0, dA0, 1); STG(sA1, dA1, 1); STG(sB0, dB0, 1); STG(sB1, dB1, 1);
  asm volatile("s_waitcnt vmcnt(8)" ::: "memory");
  __builtin_amdgcn_s_barrier();
  asm volatile("" ::: "memory");

  f32x4 acc[8][4];
#pragma unroll
  for (int m = 0; m < 8; m++)
#pragma unroll
    for (int n = 0; n < 4; n++) acc[m][n] = (f32x4){0.f, 0.f, 0.f, 0.f};

  const int xsw = (li & 7) << 3;
  const int k0o = (lg * 8) ^ xsw;
  const int k1o = (32 + lg * 8) ^ xsw;
  const u16* aBase = lds + wm * 8192;
  const u16* bBase = lds + 32768 + (wn >> 1) * 8192;
  const int brow0 = (wn & 1) * 64;

  bf16x8 a[4][2], b[4][2];

  for (int t = 0; t < NT; ++t) {
    const int db = t & 1;
    const u16* Ab = aBase + db * 16384;
    const u16* Bb = bBase + db * 16384;

    // ---- phase 0: read A[mf0-3], B[nf0-1]; MFMA (lo,lo) ----
#pragma unroll
    for (int mf = 0; mf < 4; mf++) {
      int r = mf * 16 + li;
      a[mf][0] = *(const bf16x8*)(Ab + r * 64 + k0o);
      a[mf][1] = *(const bf16x8*)(Ab + r * 64 + k1o);
    }
#pragma unroll
    for (int nf = 0; nf < 2; nf++) {
      int r = brow0 + nf * 16 + li;
      b[nf][0] = *(const bf16x8*)(Bb + r * 64 + k0o);
      b[nf][1] = *(const bf16x8*)(Bb + r * 64 + k1o);
    }
    PH_PRE();
#pragma unroll
    for (int mf = 0; mf < 4; mf++)
#pragma unroll
      for (int nf = 0; nf < 2; nf++) {
        acc[mf][nf] = __builtin_amdgcn_mfma_f32_16x16x32_bf16(a[mf][0], b[nf][0], acc[mf][nf], 0, 0, 0);
        acc[mf][nf] = __builtin_amdgcn_mfma_f32_16x16x32_bf16(a[mf][1], b[nf][1], acc[mf][nf], 0, 0, 0);
      }
    PH_POST();

    // ---- phase 1: read B[nf2-3]; MFMA (lo,hi) ----
#pragma unroll
    for (int nf = 2; nf < 4; nf++) {
      int r = brow0 + nf * 16 + li;
      b[nf][0] = *(const bf16x8*)(Bb + r * 64 + k0o);
      b[nf][1] = *(const bf16x8*)(Bb + r * 64 + k1o);
    }
    PH_PRE();
#pragma unroll
    for (int mf = 0; mf < 4; mf++)
#pragma unroll
      for (int nf = 2; nf < 4; nf++) {
        acc[mf][nf] = __builtin_amdgcn_mfma_f32_16x16x32_bf16(a[mf][0], b[nf][0], acc[mf][nf], 0, 0, 0);
        acc[mf][nf] = __builtin_amdgcn_mfma_f32_16x16x32_bf16(a[mf][1], b[nf][1], acc[mf][nf], 0, 0, 0);
      }
    PH_POST();

    // ---- phase 2: read A[mf4-7]; stage B0,B1(t+2); MFMA (hi,hi) ----
#pragma unroll
    for (int mf = 0; mf < 4; mf++) {
      int r = (mf + 4) * 16 + li;
      a[mf][0] = *(const bf16x8*)(Ab + r * 64 + k0o);
      a[mf][1] = *(const bf16x8*)(Ab + r * 64 + k1o);
    }
    if (t + 2 < NT) { STG(sB0, dB0, t + 2); STG(sB1, dB1, t + 2); }
    PH_PRE();
#pragma unroll
    for (int mf = 0; mf < 4; mf++)
#pragma unroll
      for (int nf = 2; nf < 4; nf++) {
        acc[mf + 4][nf] = __builtin_amdgcn_mfma_f32_16x16x32_bf16(a[mf][0], b[nf][0], acc[mf + 4][nf], 0, 0, 0);
        acc[mf + 4][nf] = __builtin_amdgcn_mfma_f32_16x16x32_bf16(a[mf][1], b[nf][1], acc[mf + 4][nf], 0, 0, 0);
      }
    PH_POST();

    // ---- phase 3: stage A0,A1(t+2); MFMA (hi,lo); boundary ----
    if (t + 2 < NT) { STG(sA0, dA0, t + 2); STG(sA1, dA1, t + 2); }
    PH_PRE();
#pragma unroll
    for (int mf = 0; mf < 4; mf++)
#pragma unroll
      for (int nf = 0; nf < 2; nf++) {
        acc[mf + 4][nf] = __builtin_amdgcn_mfma_f32_16x16x32_bf16(a[mf][0], b[nf][0], acc[mf + 4][nf], 0, 0, 0);
        acc[mf + 4][nf] = __builtin_amdgcn_mfma_f32_16x16x32_bf16(a[mf][1], b[nf][1], acc[mf + 4][nf], 0, 0, 0);
      }
    __builtin_amdgcn_s_setprio(0);
    if (t < NT - 2) {
      asm volatile("s_waitcnt vmcnt(8)" ::: "memory");
    } else {
      asm volatile("s_waitcnt vmcnt(0)" ::: "memory");
    }
    __builtin_amdgcn_s_barrier();
    asm volatile("" ::: "memory");
  }

#pragma unroll
  for (int mf = 0; mf < 8; mf++)
#pragma unroll
    for (int nf = 0; nf < 4; nf++)
#pragma unroll
      for (int r = 0; r < 4; r++) {
        int gm = m0 + wm * 128 + mf * 16 + lg * 4 + r;
        int gn = n0 + wn * 64 + nf * 16 + li;
        float val = acc[mf][nf][r];
        if (MODE == 0) {
          ((u16*)Cout)[(size_t)gm * N + gn] = f2bf(val);
        } else if (MODE == 2) {
          ((float*)Cout)[(size_t)gm * N + gn] = val;
        } else {  // MODE 3: fused QKV
          if (gn < 4096) {
            ((u16*)Cout)[(size_t)gm * 4096 + gn] = f2bf(val);
          } else if (gn < 5120) {
            int c = gn - 4096;
            ((u16*)C2)[(size_t)gm * 1024 + c] = f2bf(val);
          } else {
            int c = gn - 5120;
            int bb = gm >> 11, s = gm & 2047, kvh = c >> 7, d = c & 127;
            int s2 = (s & ~31) | (((s >> 2) & 3) << 3) | (((s >> 4) & 1) << 2) | (s & 3);
            ((u16*)C3)[(size_t)((bb * 8 + kvh) * 128 + d) * 2048 + s2] = f2bf(val);
          }
        }
      }
#undef STG
}

// ---------------- flash attention v3: swapped-operand QK^T/PV, in-register softmax ----------------
__global__ __launch_bounds__(256, 2) void flash_attn_kern(const u16* __restrict__ Qg,
                                                          const u16* __restrict__ Kg,
                                                          const u16* __restrict__ VT,
                                                          u16* __restrict__ Og) {
  const int bid = blockIdx.x;
  const int qt = 63 - (bid >> 4);
  const int gh = bid & 15;
  const int b = gh >> 3, kvh = gh & 7;
  const int tid = threadIdx.x;
  const int lane = tid & 63, w = tid >> 6;
  const int li = lane & 15, lg = lane >> 4;
  const int h = kvh * 4 + w;
  const int q0 = qt << 5;
  const int nt = (qt >> 1) + 1;

  __shared__ u16 Kbuf[2][8192];
  __shared__ u16 Vbuf[2][8192];

  bf16x8 qf[2][4];
  {
    const u16* qp = Qg + ((size_t)(b * 2048 + q0 + li)) * 4096 + h * 128 + lg * 8;
#pragma unroll
    for (int m = 0; m < 2; m++)
#pragma unroll
      for (int ks = 0; ks < 4; ks++)
        qf[m][ks] = *(const bf16x8*)(qp + (size_t)(m * 16) * 4096 + ks * 32);
  }

  const u16* ksrc[4];
  const u16* vsrc[4];
#pragma unroll
  for (int i = 0; i < 4; i++) {
    int c = w * 4 + i;
    int krow = c * 4 + (lane >> 4);
    int kinner = ((lane & 15) * 16) ^ ((krow & 7) << 4);
    ksrc[i] = Kg + (size_t)(b * 2048 + krow) * 1024 + kvh * 128 + (kinner >> 1);
    int vrow = c * 8 + (lane >> 3);
    int vinner = ((lane & 7) * 16) ^ ((vrow & 7) << 4);
    vsrc[i] = VT + (size_t)((b * 8 + kvh) * 128 + vrow) * 2048 + (vinner >> 1);
  }
#pragma unroll
  for (int i = 0; i < 4; i++) {
    int c = w * 4 + i;
    gload16(ksrc[i], &Kbuf[0][c * 512]);
    gload16(vsrc[i], &Vbuf[0][c * 512]);
    ksrc[i] += 64 * 1024;
    vsrc[i] += 64;
  }

  f32x4 oa[2][8];
#pragma unroll
  for (int m = 0; m < 2; m++)
#pragma unroll
    for (int n = 0; n < 8; n++) oa[m][n] = (f32x4){0.f, 0.f, 0.f, 0.f};
  f32x4 lacc[2];
  lacc[0] = (f32x4){0.f, 0.f, 0.f, 0.f};
  lacc[1] = (f32x4){0.f, 0.f, 0.f, 0.f};
  float mrun[2] = {-1e30f, -1e30f};

  const float scale = 0.08838834764831845f;
  bf16x8 onesf;
#pragma unroll
  for (int j = 0; j < 8; j++) onesf[j] = (short)0x3F80;

  asm volatile("s_waitcnt vmcnt(0)\n\ts_barrier" ::: "memory");

  for (int t = 0; t < nt; ++t) {
    const int cur = t & 1;
    const u16* KB = Kbuf[cur];
    const u16* VB = Vbuf[cur];
    if (t + 1 < nt) {
#pragma unroll
      for (int i = 0; i < 4; i++) {
        int c = w * 4 + i;
        gload16(ksrc[i], &Kbuf[cur ^ 1][c * 512]);
        gload16(vsrc[i], &Vbuf[cur ^ 1][c * 512]);
        ksrc[i] += 64 * 1024;
        vsrc[i] += 64;
      }
    }

    f32x4 sacc[2][4];
#pragma unroll
    for (int m = 0; m < 2; m++)
#pragma unroll
      for (int n = 0; n < 4; n++) sacc[m][n] = (f32x4){0.f, 0.f, 0.f, 0.f};
    __builtin_amdgcn_s_setprio(1);
#pragma unroll
    for (int n = 0; n < 4; n++) {
      int krow = n * 16 + li;
      const u16* kb = KB + krow * 128;
      int sw = (krow & 7) << 4;
#pragma unroll
      for (int ks = 0; ks < 4; ks++) {
        bf16x8 kf = *(const bf16x8*)(kb + (((ks * 64 + lg * 16) ^ sw) >> 1));
        sacc[0][n] = __builtin_amdgcn_mfma_f32_16x16x32_bf16(kf, qf[0][ks], sacc[0][n], 0, 0, 0);
        sacc[1][n] = __builtin_amdgcn_mfma_f32_16x16x32_bf16(kf, qf[1][ks], sacc[1][n], 0, 0, 0);
      }
    }
    __builtin_amdgcn_s_setprio(0);

#pragma unroll
    for (int m = 0; m < 2; m++)
#pragma unroll
      for (int n = 0; n < 4; n++)
#pragma unroll
        for (int r = 0; r < 4; r++) sacc[m][n][r] *= scale;
    if (t == nt - 1) {
      const int kv0 = t * 64;
#pragma unroll
      for (int m = 0; m < 2; m++) {
        int q = q0 + m * 16 + li;
#pragma unroll
        for (int n = 0; n < 4; n++)
#pragma unroll
          for (int r = 0; r < 4; r++)
            if (kv0 + n * 16 + lg * 4 + r > q) sacc[m][n][r] = -1e30f;
      }
    }

#pragma unroll
    for (int m = 0; m < 2; m++) {
      float mx = sacc[m][0][0];
#pragma unroll
      for (int n = 0; n < 4; n++)
#pragma unroll
        for (int r = 0; r < 4; r++) mx = fmaxf(mx, sacc[m][n][r]);
      mx = fmaxf(mx, __shfl_xor(mx, 16, 64));
      mx = fmaxf(mx, __shfl_xor(mx, 32, 64));
      float mnew = fmaxf(mrun[m], mx);
      float corr = __expf(mrun[m] - mnew);
      mrun[m] = mnew;
#pragma unroll
      for (int n = 0; n < 4; n++)
#pragma unroll
        for (int r = 0; r < 4; r++) sacc[m][n][r] = __expf(sacc[m][n][r] - mnew);
#pragma unroll
      for (int r = 0; r < 4; r++) lacc[m][r] *= corr;
#pragma unroll
      for (int n = 0; n < 8; n++)
#pragma unroll
        for (int r = 0; r < 4; r++) oa[m][n][r] *= corr;
    }

    bf16x8 pf[2][2];
#pragma unroll
    for (int m = 0; m < 2; m++)
#pragma unroll
      for (int kvs = 0; kvs < 2; kvs++) {
        u16x8 pw;
#pragma unroll
        for (int e = 0; e < 8; e++) pw[e] = f2bf(sacc[m][2 * kvs + (e >> 2)][e & 3]);
        pf[m][kvs] = *(bf16x8*)&pw;
      }

    __builtin_amdgcn_s_setprio(1);
#pragma unroll
    for (int kvs = 0; kvs < 2; kvs++) {
#pragma unroll
      for (int n = 0; n < 8; n++) {
        int vrow = n * 16 + li;
        bf16x8 vf = *(const bf16x8*)(VB + vrow * 64 +
                                     (((kvs * 64 + lg * 16) ^ ((vrow & 7) << 4)) >> 1));
        oa[0][n] = __builtin_amdgcn_mfma_f32_16x16x32_bf16(vf, pf[0][kvs], oa[0][n], 0, 0, 0);
        oa[1][n] = __builtin_amdgcn_mfma_f32_16x16x32_bf16(vf, pf[1][kvs], oa[1][n], 0, 0, 0);
      }
      lacc[0] = __builtin_amdgcn_mfma_f32_16x16x32_bf16(onesf, pf[0][kvs], lacc[0], 0, 0, 0);
      lacc[1] = __builtin_amdgcn_mfma_f32_16x16x32_bf16(onesf, pf[1][kvs], lacc[1], 0, 0, 0);
    }
    __builtin_amdgcn_s_setprio(0);

    asm volatile("s_waitcnt vmcnt(0)\n\ts_barrier" ::: "memory");
  }

#pragma unroll
  for (int m = 0; m < 2; m++) {
    float inv = 1.0f / lacc[m][0];
    u16* op = Og + (size_t)(b * 2048 + q0 + m * 16 + li) * 4096 + h * 128 + lg * 4;
#pragma unroll
    for (int n = 0; n < 8; n++) {
      u16x4 o;
#pragma unroll
      for (int r = 0; r < 4; r++) o[r] = f2bf(oa[m][n][r] * inv);
      *(u16x4*)(op + n * 16) = o;
    }
  }
}

extern "C" void kernel_launch(void* const* d_in, const int* in_sizes, int n_in,
                              void* d_out, int out_size, void* d_ws, size_t ws_size,
                              hipStream_t stream) {
  (void)in_sizes; (void)n_in; (void)out_size; (void)ws_size;
  const float* hs = (const float*)d_in[0];
  const float* wq = (const float*)d_in[1];
  const float* wk = (const float*)d_in[2];
  const float* wv = (const float*)d_in[3];
  const float* wo = (const float*)d_in[4];

  u16* ws   = (u16*)d_ws;
  u16* hs_b = ws;               // [4096][4096]
  u16* wqT  = hs_b + 16777216;  // [4096][4096]   (contiguous with wkT, wvT -> [6144][4096])
  u16* wkT  = wqT + 16777216;   // [1024][4096]
  u16* wvT  = wkT + 4194304;    // [1024][4096]
  u16* woT  = wvT + 4194304;    // [4096][4096]
  u16* Qb   = woT + 16777216;   // [4096][4096]
  u16* Kb   = Qb + 16777216;    // [4096][1024]
  u16* VTb  = Kb + 4194304;     // [2][8][128][2048] (kv-axis permuted)
  u16* attnb = VTb + 4194304;   // [4096][4096]

  prep_kern<<<18432, 256, 0, stream>>>(hs, wq, wk, wv, wo, hs_b, wqT, wkT, wvT, woT);

  // fused Q/K/V projection: one 4096x6144x4096 GEMM (B = wqT|wkT|wvT contiguous)
  gemm256<3><<<384, 512, 0, stream>>>(hs_b, wqT, Qb, Kb, VTb, 4096, 6144, 4096);

  flash_attn_kern<<<1024, 256, 0, stream>>>(Qb, Kb, VTb, attnb);

  gemm256<2><<<256, 512, 0, stream>>>(attnb, woT, (float*)d_out, nullptr, nullptr,
                                      4096, 4096, 4096);
}

// Round 17
// 471.275 us; speedup vs baseline: 1.1121x; 1.1121x over previous
//
#include <hip/hip_runtime.h>

typedef unsigned short u16;
typedef __attribute__((ext_vector_type(8))) short bf16x8;
typedef __attribute__((ext_vector_type(8))) unsigned short u16x8;
typedef __attribute__((ext_vector_type(4))) unsigned short u16x4;
typedef __attribute__((ext_vector_type(4))) float f32x4;

__device__ __forceinline__ u16 f2bf(float f) {
  union { float f; unsigned u; } v; v.f = f;
  unsigned r = v.u + 0x7fffu + ((v.u >> 16) & 1u);
  return (u16)(r >> 16);
}

__device__ __forceinline__ void gload16(const u16* g, u16* l) {
  __builtin_amdgcn_global_load_lds((const __attribute__((address_space(1))) void*)g,
                                   (__attribute__((address_space(3))) void*)l, 16, 0, 0);
}

// ---------------- fused prep: cast hs + 4 transpose-casts, one launch ----------------
__device__ __forceinline__ void transpose_body(const float* __restrict__ in,
                                               u16* __restrict__ out, int K, int N,
                                               int bid, float (*tile)[65]) {
  int nbx = N >> 6;
  int n0 = (bid % nbx) << 6;
  int k0 = (bid / nbx) << 6;
  int tx = threadIdx.x & 15;
  int ty = threadIdx.x >> 4;
#pragma unroll
  for (int r = 0; r < 64; r += 16) {
    float4 v = *(const float4*)(in + (size_t)(k0 + ty + r) * N + n0 + tx * 4);
    tile[ty + r][tx * 4 + 0] = v.x;
    tile[ty + r][tx * 4 + 1] = v.y;
    tile[ty + r][tx * 4 + 2] = v.z;
    tile[ty + r][tx * 4 + 3] = v.w;
  }
  __syncthreads();
#pragma unroll
  for (int r = 0; r < 64; r += 16) {
    u16x4 o;
#pragma unroll
    for (int j = 0; j < 4; j++) o[j] = f2bf(tile[tx * 4 + j][ty + r]);
    *(u16x4*)(out + (size_t)(n0 + ty + r) * K + k0 + tx * 4) = o;
  }
}

__global__ __launch_bounds__(256) void prep_kern(const float* __restrict__ hs,
                                                 const float* __restrict__ wq,
                                                 const float* __restrict__ wk,
                                                 const float* __restrict__ wv,
                                                 const float* __restrict__ wo,
                                                 u16* __restrict__ hs_b,
                                                 u16* __restrict__ wqT,
                                                 u16* __restrict__ wkT,
                                                 u16* __restrict__ wvT,
                                                 u16* __restrict__ woT) {
  __shared__ float tile[64][65];
  int b = blockIdx.x;
  if (b < 8192) {
    int i = (b * 256 + threadIdx.x) * 8;
    float4 a = *(const float4*)(hs + i);
    float4 c = *(const float4*)(hs + i + 4);
    u16x8 r;
    r[0] = f2bf(a.x); r[1] = f2bf(a.y); r[2] = f2bf(a.z); r[3] = f2bf(a.w);
    r[4] = f2bf(c.x); r[5] = f2bf(c.y); r[6] = f2bf(c.z); r[7] = f2bf(c.w);
    *(u16x8*)(hs_b + i) = r;
  } else if (b < 12288) {
    transpose_body(wq, wqT, 4096, 4096, b - 8192, tile);
  } else if (b < 13312) {
    transpose_body(wk, wkT, 4096, 1024, b - 12288, tile);
  } else if (b < 14336) {
    transpose_body(wv, wvT, 4096, 1024, b - 13312, tile);
  } else {
    transpose_body(wo, woT, 4096, 4096, b - 14336, tile);
  }
}

// ---- phase fences (measured-best round-7 structure) ----
#define PH_PRE()                                           \
  asm volatile("" ::: "memory");                           \
  __builtin_amdgcn_s_barrier();                            \
  asm volatile("" ::: "memory");                           \
  __builtin_amdgcn_s_setprio(1)

#define PH_POST()                                          \
  __builtin_amdgcn_s_setprio(0);                           \
  asm volatile("" ::: "memory");                           \
  __builtin_amdgcn_s_barrier();                            \
  asm volatile("" ::: "memory")

// ---------------- 256^2 8-phase GEMM (measured-best: 138 us, MfmaUtil 42%) ----------------
template <int MODE>
__global__ __launch_bounds__(512, 2) void gemm256(const u16* __restrict__ A,
                                                  const u16* __restrict__ Bt,
                                                  void* __restrict__ Cout,
                                                  int M, int N, int K) {
  __shared__ u16 lds[65536];  // 128 KiB: A at 0, B at 32768 (u16 units)
  const int tid = threadIdx.x;
  const int lane = tid & 63, w = tid >> 6;
  const int wm = w >> 2, wn = w & 3;
  const int li = lane & 15, lg = lane >> 4;
  const int NT = K >> 6;

  const int nbx = N >> 8;
  const int nwg = gridDim.x;
  const int swz = (blockIdx.x & 7) * (nwg >> 3) + (blockIdx.x >> 3);  // XCD swizzle (nwg%8==0)
  const int m0 = (swz / nbx) << 8;
  const int n0 = (swz % nbx) << 8;

  const int srow = w * 16 + (lane >> 3);
  const int scol = ((lane & 7) ^ (lane >> 3)) << 3;
  const u16* sA0 = A + (size_t)(m0 + srow) * K + scol;
  const u16* sA1 = A + (size_t)(m0 + 128 + srow) * K + scol;
  const u16* sB0 = Bt + (size_t)(n0 + srow) * K + scol;
  const u16* sB1 = Bt + (size_t)(n0 + 128 + srow) * K + scol;
  const size_t jK = (size_t)8 * K;
  u16* dA0 = lds + w * 1024;
  u16* dA1 = lds + 8192 + w * 1024;
  u16* dB0 = lds + 32768 + w * 1024;
  u16* dB1 = lds + 32768 + 8192 + w * 1024;

#define STG(sp, dp, t_) do {                                          \
    int db_ = (t_) & 1;                                               \
    gload16((sp) + (size_t)(t_) * 64, (dp) + db_ * 16384);            \
    gload16((sp) + (size_t)(t_) * 64 + jK, (dp) + db_ * 16384 + 512); \
  } while (0)

  STG(sA0, dA0, 0); STG(sA1, dA1, 0); STG(sB0, dB0, 0); STG(sB1, dB1, 0);
  STG(sA0, dA0, 1); STG(sA1, dA1, 1); STG(sB0, dB0, 1); STG(sB1, dB1, 1);
  asm volatile("s_waitcnt vmcnt(8)" ::: "memory");
  __builtin_amdgcn_s_barrier();
  asm volatile("" ::: "memory");

  f32x4 acc[8][4];
#pragma unroll
  for (int m = 0; m < 8; m++)
#pragma unroll
    for (int n = 0; n < 4; n++) acc[m][n] = (f32x4){0.f, 0.f, 0.f, 0.f};

  const int xsw = (li & 7) << 3;
  const int k0o = (lg * 8) ^ xsw;
  const int k1o = (32 + lg * 8) ^ xsw;
  const u16* aBase = lds + wm * 8192;
  const u16* bBase = lds + 32768 + (wn >> 1) * 8192;
  const int brow0 = (wn & 1) * 64;

  bf16x8 a[4][2], b[4][2];

  for (int t = 0; t < NT; ++t) {
    const int db = t & 1;
    const u16* Ab = aBase + db * 16384;
    const u16* Bb = bBase + db * 16384;

    // ---- phase 0: read A[mf0-3], B[nf0-1]; MFMA (lo,lo) ----
#pragma unroll
    for (int mf = 0; mf < 4; mf++) {
      int r = mf * 16 + li;
      a[mf][0] = *(const bf16x8*)(Ab + r * 64 + k0o);
      a[mf][1] = *(const bf16x8*)(Ab + r * 64 + k1o);
    }
#pragma unroll
    for (int nf = 0; nf < 2; nf++) {
      int r = brow0 + nf * 16 + li;
      b[nf][0] = *(const bf16x8*)(Bb + r * 64 + k0o);
      b[nf][1] = *(const bf16x8*)(Bb + r * 64 + k1o);
    }
    PH_PRE();
#pragma unroll
    for (int mf = 0; mf < 4; mf++)
#pragma unroll
      for (int nf = 0; nf < 2; nf++) {
        acc[mf][nf] = __builtin_amdgcn_mfma_f32_16x16x32_bf16(a[mf][0], b[nf][0], acc[mf][nf], 0, 0, 0);
        acc[mf][nf] = __builtin_amdgcn_mfma_f32_16x16x32_bf16(a[mf][1], b[nf][1], acc[mf][nf], 0, 0, 0);
      }
    PH_POST();

    // ---- phase 1: read B[nf2-3]; MFMA (lo,hi) ----
#pragma unroll
    for (int nf = 2; nf < 4; nf++) {
      int r = brow0 + nf * 16 + li;
      b[nf][0] = *(const bf16x8*)(Bb + r * 64 + k0o);
      b[nf][1] = *(const bf16x8*)(Bb + r * 64 + k1o);
    }
    PH_PRE();
#pragma unroll
    for (int mf = 0; mf < 4; mf++)
#pragma unroll
      for (int nf = 2; nf < 4; nf++) {
        acc[mf][nf] = __builtin_amdgcn_mfma_f32_16x16x32_bf16(a[mf][0], b[nf][0], acc[mf][nf], 0, 0, 0);
        acc[mf][nf] = __builtin_amdgcn_mfma_f32_16x16x32_bf16(a[mf][1], b[nf][1], acc[mf][nf], 0, 0, 0);
      }
    PH_POST();

    // ---- phase 2: read A[mf4-7]; stage B0,B1(t+2); MFMA (hi,hi) ----
#pragma unroll
    for (int mf = 0; mf < 4; mf++) {
      int r = (mf + 4) * 16 + li;
      a[mf][0] = *(const bf16x8*)(Ab + r * 64 + k0o);
      a[mf][1] = *(const bf16x8*)(Ab + r * 64 + k1o);
    }
    if (t + 2 < NT) { STG(sB0, dB0, t + 2); STG(sB1, dB1, t + 2); }
    PH_PRE();
#pragma unroll
    for (int mf = 0; mf < 4; mf++)
#pragma unroll
      for (int nf = 2; nf < 4; nf++) {
        acc[mf + 4][nf] = __builtin_amdgcn_mfma_f32_16x16x32_bf16(a[mf][0], b[nf][0], acc[mf + 4][nf], 0, 0, 0);
        acc[mf + 4][nf] = __builtin_amdgcn_mfma_f32_16x16x32_bf16(a[mf][1], b[nf][1], acc[mf + 4][nf], 0, 0, 0);
      }
    PH_POST();

    // ---- phase 3: stage A0,A1(t+2); MFMA (hi,lo); boundary ----
    if (t + 2 < NT) { STG(sA0, dA0, t + 2); STG(sA1, dA1, t + 2); }
    PH_PRE();
#pragma unroll
    for (int mf = 0; mf < 4; mf++)
#pragma unroll
      for (int nf = 0; nf < 2; nf++) {
        acc[mf + 4][nf] = __builtin_amdgcn_mfma_f32_16x16x32_bf16(a[mf][0], b[nf][0], acc[mf + 4][nf], 0, 0, 0);
        acc[mf + 4][nf] = __builtin_amdgcn_mfma_f32_16x16x32_bf16(a[mf][1], b[nf][1], acc[mf + 4][nf], 0, 0, 0);
      }
    __builtin_amdgcn_s_setprio(0);
    if (t < NT - 2) {
      asm volatile("s_waitcnt vmcnt(8)" ::: "memory");
    } else {
      asm volatile("s_waitcnt vmcnt(0)" ::: "memory");
    }
    __builtin_amdgcn_s_barrier();
    asm volatile("" ::: "memory");
  }

#pragma unroll
  for (int mf = 0; mf < 8; mf++)
#pragma unroll
    for (int nf = 0; nf < 4; nf++)
#pragma unroll
      for (int r = 0; r < 4; r++) {
        int gm = m0 + wm * 128 + mf * 16 + lg * 4 + r;
        int gn = n0 + wn * 64 + nf * 16 + li;
        if (MODE == 0)
          ((u16*)Cout)[(size_t)gm * N + gn] = f2bf(acc[mf][nf][r]);
        else
          ((float*)Cout)[(size_t)gm * N + gn] = acc[mf][nf][r];
      }
#undef STG
}

// ---------------- KV projection GEMM: M=4096 N=2048 K=4096; BM=128 BN=256 BK=64 ----------------
__global__ __launch_bounds__(512, 2) void gemm_kv(const u16* __restrict__ A,
                                                  const u16* __restrict__ Bt,
                                                  u16* __restrict__ Kout,
                                                  u16* __restrict__ Vout) {
  __shared__ u16 lds[49152];  // A: 2 x 8192 u16 at 0; B: 2 x 16384 u16 at 16384
  const int tid = threadIdx.x;
  const int lane = tid & 63, w = tid >> 6;
  const int wm = w >> 2, wn = w & 3;
  const int li = lane & 15, lg = lane >> 4;
  const int K = 4096, NT = 64;

  const int swz = (blockIdx.x & 7) * 32 + (blockIdx.x >> 3);  // 256 blocks, XCD swizzle
  const int m0 = (swz >> 3) << 7;   // 32 M-tiles
  const int n0 = (swz & 7) << 8;    // 8 N-tiles

  const int srow = w * 16 + (lane >> 3);
  const int scol = ((lane & 7) ^ (lane >> 3)) << 3;
  const u16* sA  = A  + (size_t)(m0 + srow) * K + scol;
  const u16* sB0 = Bt + (size_t)(n0 + srow) * K + scol;
  const u16* sB1 = Bt + (size_t)(n0 + 128 + srow) * K + scol;
  const size_t jK = (size_t)8 * K;
  u16* dA  = lds + w * 1024;
  u16* dB0 = lds + 16384 + w * 1024;
  u16* dB1 = lds + 16384 + 8192 + w * 1024;

#define STGA(t_) do { int db_ = (t_) & 1;                                     \
    gload16(sA + (size_t)(t_) * 64, dA + db_ * 8192);                         \
    gload16(sA + (size_t)(t_) * 64 + jK, dA + db_ * 8192 + 512); } while (0)
#define STGB(t_) do { int db_ = (t_) & 1;                                     \
    gload16(sB0 + (size_t)(t_) * 64, dB0 + db_ * 16384);                      \
    gload16(sB0 + (size_t)(t_) * 64 + jK, dB0 + db_ * 16384 + 512);           \
    gload16(sB1 + (size_t)(t_) * 64, dB1 + db_ * 16384);                      \
    gload16(sB1 + (size_t)(t_) * 64 + jK, dB1 + db_ * 16384 + 512); } while (0)

  STGA(0); STGB(0); STGB(1);
  asm volatile("s_waitcnt vmcnt(4)" ::: "memory");
  __builtin_amdgcn_s_barrier();
  asm volatile("" ::: "memory");

  f32x4 acc[4][4];
#pragma unroll
  for (int m = 0; m < 4; m++)
#pragma unroll
    for (int n = 0; n < 4; n++) acc[m][n] = (f32x4){0.f, 0.f, 0.f, 0.f};

  const int xsw = (li & 7) << 3;
  const int k0o = (lg * 8) ^ xsw;
  const int k1o = (32 + lg * 8) ^ xsw;
  const int arow0 = wm * 64;
  const u16* bBase0 = lds + 16384 + (wn >> 1) * 8192;
  const int brow0 = (wn & 1) * 64;

  bf16x8 a[4][2], b[4][2];

  for (int t = 0; t < NT; ++t) {
    const int db = t & 1;
    const u16* Ab = lds + db * 8192;
    const u16* Bb = bBase0 + db * 16384;

    // ---- phase 0: read A[mf0-1], B[nf0-3]; stage A(t+1) (opposite parity); MFMA lo ----
#pragma unroll
    for (int mf = 0; mf < 2; mf++) {
      int r = arow0 + mf * 16 + li;
      a[mf][0] = *(const bf16x8*)(Ab + r * 64 + k0o);
      a[mf][1] = *(const bf16x8*)(Ab + r * 64 + k1o);
    }
#pragma unroll
    for (int nf = 0; nf < 4; nf++) {
      int r = brow0 + nf * 16 + li;
      b[nf][0] = *(const bf16x8*)(Bb + r * 64 + k0o);
      b[nf][1] = *(const bf16x8*)(Bb + r * 64 + k1o);
    }
    if (t + 1 < NT) STGA(t + 1);
    PH_PRE();
#pragma unroll
    for (int mf = 0; mf < 2; mf++)
#pragma unroll
      for (int nf = 0; nf < 4; nf++) {
        acc[mf][nf] = __builtin_amdgcn_mfma_f32_16x16x32_bf16(a[mf][0], b[nf][0], acc[mf][nf], 0, 0, 0);
        acc[mf][nf] = __builtin_amdgcn_mfma_f32_16x16x32_bf16(a[mf][1], b[nf][1], acc[mf][nf], 0, 0, 0);
      }
    PH_POST();

    // ---- phase 1: read A[mf2-3]; stage B(t+2); MFMA hi; boundary ----
#pragma unroll
    for (int mf = 2; mf < 4; mf++) {
      int r = arow0 + mf * 16 + li;
      a[mf][0] = *(const bf16x8*)(Ab + r * 64 + k0o);
      a[mf][1] = *(const bf16x8*)(Ab + r * 64 + k1o);
    }
    if (t + 2 < NT) STGB(t + 2);
    PH_PRE();
#pragma unroll
    for (int mf = 2; mf < 4; mf++)
#pragma unroll
      for (int nf = 0; nf < 4; nf++) {
        acc[mf][nf] = __builtin_amdgcn_mfma_f32_16x16x32_bf16(a[mf][0], b[nf][0], acc[mf][nf], 0, 0, 0);
        acc[mf][nf] = __builtin_amdgcn_mfma_f32_16x16x32_bf16(a[mf][1], b[nf][1], acc[mf][nf], 0, 0, 0);
      }
    __builtin_amdgcn_s_setprio(0);
    if (t < NT - 2) {
      asm volatile("s_waitcnt vmcnt(4)" ::: "memory");
    } else {
      asm volatile("s_waitcnt vmcnt(0)" ::: "memory");
    }
    __builtin_amdgcn_s_barrier();
    asm volatile("" ::: "memory");
  }

#pragma unroll
  for (int mf = 0; mf < 4; mf++)
#pragma unroll
    for (int nf = 0; nf < 4; nf++)
#pragma unroll
      for (int r = 0; r < 4; r++) {
        int gm = m0 + wm * 64 + mf * 16 + lg * 4 + r;
        int gn = n0 + wn * 64 + nf * 16 + li;
        float val = acc[mf][nf][r];
        if (gn < 1024) {
          Kout[(size_t)gm * 1024 + gn] = f2bf(val);
        } else {
          int c = gn - 1024;
          int b = gm >> 11, s = gm & 2047, kvh = c >> 7, d = c & 127;
          int s2 = (s & ~31) | (((s >> 2) & 3) << 3) | (((s >> 4) & 1) << 2) | (s & 3);
          Vout[(size_t)((b * 8 + kvh) * 128 + d) * 2048 + s2] = f2bf(val);
        }
      }
#undef STGA
#undef STGB
}

// ---------------- flash attention v3: swapped-operand QK^T/PV, in-register softmax ----------------
__global__ __launch_bounds__(256, 2) void flash_attn_kern(const u16* __restrict__ Qg,
                                                          const u16* __restrict__ Kg,
                                                          const u16* __restrict__ VT,
                                                          u16* __restrict__ Og) {
  const int bid = blockIdx.x;
  const int qt = 63 - (bid >> 4);
  const int gh = bid & 15;
  const int b = gh >> 3, kvh = gh & 7;
  const int tid = threadIdx.x;
  const int lane = tid & 63, w = tid >> 6;
  const int li = lane & 15, lg = lane >> 4;
  const int h = kvh * 4 + w;
  const int q0 = qt << 5;
  const int nt = (qt >> 1) + 1;

  __shared__ u16 Kbuf[2][8192];
  __shared__ u16 Vbuf[2][8192];

  bf16x8 qf[2][4];
  {
    const u16* qp = Qg + ((size_t)(b * 2048 + q0 + li)) * 4096 + h * 128 + lg * 8;
#pragma unroll
    for (int m = 0; m < 2; m++)
#pragma unroll
      for (int ks = 0; ks < 4; ks++)
        qf[m][ks] = *(const bf16x8*)(qp + (size_t)(m * 16) * 4096 + ks * 32);
  }

  const u16* ksrc[4];
  const u16* vsrc[4];
#pragma unroll
  for (int i = 0; i < 4; i++) {
    int c = w * 4 + i;
    int krow = c * 4 + (lane >> 4);
    int kinner = ((lane & 15) * 16) ^ ((krow & 7) << 4);
    ksrc[i] = Kg + (size_t)(b * 2048 + krow) * 1024 + kvh * 128 + (kinner >> 1);
    int vrow = c * 8 + (lane >> 3);
    int vinner = ((lane & 7) * 16) ^ ((vrow & 7) << 4);
    vsrc[i] = VT + (size_t)((b * 8 + kvh) * 128 + vrow) * 2048 + (vinner >> 1);
  }
#pragma unroll
  for (int i = 0; i < 4; i++) {
    int c = w * 4 + i;
    gload16(ksrc[i], &Kbuf[0][c * 512]);
    gload16(vsrc[i], &Vbuf[0][c * 512]);
    ksrc[i] += 64 * 1024;
    vsrc[i] += 64;
  }

  f32x4 oa[2][8];
#pragma unroll
  for (int m = 0; m < 2; m++)
#pragma unroll
    for (int n = 0; n < 8; n++) oa[m][n] = (f32x4){0.f, 0.f, 0.f, 0.f};
  f32x4 lacc[2];
  lacc[0] = (f32x4){0.f, 0.f, 0.f, 0.f};
  lacc[1] = (f32x4){0.f, 0.f, 0.f, 0.f};
  float mrun[2] = {-1e30f, -1e30f};

  const float scale = 0.08838834764831845f;
  bf16x8 onesf;
#pragma unroll
  for (int j = 0; j < 8; j++) onesf[j] = (short)0x3F80;

  asm volatile("s_waitcnt vmcnt(0)\n\ts_barrier" ::: "memory");

  for (int t = 0; t < nt; ++t) {
    const int cur = t & 1;
    const u16* KB = Kbuf[cur];
    const u16* VB = Vbuf[cur];
    if (t + 1 < nt) {
#pragma unroll
      for (int i = 0; i < 4; i++) {
        int c = w * 4 + i;
        gload16(ksrc[i], &Kbuf[cur ^ 1][c * 512]);
        gload16(vsrc[i], &Vbuf[cur ^ 1][c * 512]);
        ksrc[i] += 64 * 1024;
        vsrc[i] += 64;
      }
    }

    f32x4 sacc[2][4];
#pragma unroll
    for (int m = 0; m < 2; m++)
#pragma unroll
      for (int n = 0; n < 4; n++) sacc[m][n] = (f32x4){0.f, 0.f, 0.f, 0.f};
    __builtin_amdgcn_s_setprio(1);
#pragma unroll
    for (int n = 0; n < 4; n++) {
      int krow = n * 16 + li;
      const u16* kb = KB + krow * 128;
      int sw = (krow & 7) << 4;
#pragma unroll
      for (int ks = 0; ks < 4; ks++) {
        bf16x8 kf = *(const bf16x8*)(kb + (((ks * 64 + lg * 16) ^ sw) >> 1));
        sacc[0][n] = __builtin_amdgcn_mfma_f32_16x16x32_bf16(kf, qf[0][ks], sacc[0][n], 0, 0, 0);
        sacc[1][n] = __builtin_amdgcn_mfma_f32_16x16x32_bf16(kf, qf[1][ks], sacc[1][n], 0, 0, 0);
      }
    }
    __builtin_amdgcn_s_setprio(0);

#pragma unroll
    for (int m = 0; m < 2; m++)
#pragma unroll
      for (int n = 0; n < 4; n++)
#pragma unroll
        for (int r = 0; r < 4; r++) sacc[m][n][r] *= scale;
    if (t == nt - 1) {
      const int kv0 = t * 64;
#pragma unroll
      for (int m = 0; m < 2; m++) {
        int q = q0 + m * 16 + li;
#pragma unroll
        for (int n = 0; n < 4; n++)
#pragma unroll
          for (int r = 0; r < 4; r++)
            if (kv0 + n * 16 + lg * 4 + r > q) sacc[m][n][r] = -1e30f;
      }
    }

#pragma unroll
    for (int m = 0; m < 2; m++) {
      float mx = sacc[m][0][0];
#pragma unroll
      for (int n = 0; n < 4; n++)
#pragma unroll
        for (int r = 0; r < 4; r++) mx = fmaxf(mx, sacc[m][n][r]);
      mx = fmaxf(mx, __shfl_xor(mx, 16, 64));
      mx = fmaxf(mx, __shfl_xor(mx, 32, 64));
      float mnew = fmaxf(mrun[m], mx);
      float corr = __expf(mrun[m] - mnew);
      mrun[m] = mnew;
#pragma unroll
      for (int n = 0; n < 4; n++)
#pragma unroll
        for (int r = 0; r < 4; r++) sacc[m][n][r] = __expf(sacc[m][n][r] - mnew);
#pragma unroll
      for (int r = 0; r < 4; r++) lacc[m][r] *= corr;
#pragma unroll
      for (int n = 0; n < 8; n++)
#pragma unroll
        for (int r = 0; r < 4; r++) oa[m][n][r] *= corr;
    }

    bf16x8 pf[2][2];
#pragma unroll
    for (int m = 0; m < 2; m++)
#pragma unroll
      for (int kvs = 0; kvs < 2; kvs++) {
        u16x8 pw;
#pragma unroll
        for (int e = 0; e < 8; e++) pw[e] = f2bf(sacc[m][2 * kvs + (e >> 2)][e & 3]);
        pf[m][kvs] = *(bf16x8*)&pw;
      }

    __builtin_amdgcn_s_setprio(1);
#pragma unroll
    for (int kvs = 0; kvs < 2; kvs++) {
#pragma unroll
      for (int n = 0; n < 8; n++) {
        int vrow = n * 16 + li;
        bf16x8 vf = *(const bf16x8*)(VB + vrow * 64 +
                                     (((kvs * 64 + lg * 16) ^ ((vrow & 7) << 4)) >> 1));
        oa[0][n] = __builtin_amdgcn_mfma_f32_16x16x32_bf16(vf, pf[0][kvs], oa[0][n], 0, 0, 0);
        oa[1][n] = __builtin_amdgcn_mfma_f32_16x16x32_bf16(vf, pf[1][kvs], oa[1][n], 0, 0, 0);
      }
      lacc[0] = __builtin_amdgcn_mfma_f32_16x16x32_bf16(onesf, pf[0][kvs], lacc[0], 0, 0, 0);
      lacc[1] = __builtin_amdgcn_mfma_f32_16x16x32_bf16(onesf, pf[1][kvs], lacc[1], 0, 0, 0);
    }
    __builtin_amdgcn_s_setprio(0);

    asm volatile("s_waitcnt vmcnt(0)\n\ts_barrier" ::: "memory");
  }

#pragma unroll
  for (int m = 0; m < 2; m++) {
    float inv = 1.0f / lacc[m][0];
    u16* op = Og + (size_t)(b * 2048 + q0 + m * 16 + li) * 4096 + h * 128 + lg * 4;
#pragma unroll
    for (int n = 0; n < 8; n++) {
      u16x4 o;
#pragma unroll
      for (int r = 0; r < 4; r++) o[r] = f2bf(oa[m][n][r] * inv);
      *(u16x4*)(op + n * 16) = o;
    }
  }
}

extern "C" void kernel_launch(void* const* d_in, const int* in_sizes, int n_in,
                              void* d_out, int out_size, void* d_ws, size_t ws_size,
                              hipStream_t stream) {
  (void)in_sizes; (void)n_in; (void)out_size; (void)ws_size;
  const float* hs = (const float*)d_in[0];
  const float* wq = (const float*)d_in[1];
  const float* wk = (const float*)d_in[2];
  const float* wv = (const float*)d_in[3];
  const float* wo = (const float*)d_in[4];

  u16* ws   = (u16*)d_ws;
  u16* hs_b = ws;               // [4096][4096]
  u16* wqT  = hs_b + 16777216;  // [4096][4096]
  u16* wkT  = wqT + 16777216;   // [1024][4096] (contiguous with wvT -> [2048][4096])
  u16* wvT  = wkT + 4194304;    // [1024][4096]
  u16* woT  = wvT + 4194304;    // [4096][4096]
  u16* Qb   = woT + 16777216;   // [4096][4096]
  u16* Kb   = Qb + 16777216;    // [4096][1024]
  u16* VTb  = Kb + 4194304;     // [2][8][128][2048] (kv-axis permuted)
  u16* attnb = VTb + 4194304;   // [4096][4096]

  prep_kern<<<18432, 256, 0, stream>>>(hs, wq, wk, wv, wo, hs_b, wqT, wkT, wvT, woT);

  gemm256<0><<<256, 512, 0, stream>>>(hs_b, wqT, Qb, 4096, 4096, 4096);
  gemm_kv<<<256, 512, 0, stream>>>(hs_b, wkT, Kb, VTb);

  flash_attn_kern<<<1024, 256, 0, stream>>>(Qb, Kb, VTb, attnb);

  gemm256<2><<<256, 512, 0, stream>>>(attnb, woT, (float*)d_out, 4096, 4096, 4096);
}